// Round 2
// baseline (386.720 us; speedup 1.0000x reference)
//
#include <hip/hip_runtime.h>
#include <hip/hip_bf16.h>
#include <stdint.h>

#define D_MODEL 1024
#define NH 16
#define SEQ 512
#define DK 64
#define BATCH 16
#define M_TOT (BATCH*SEQ)   // 8192

typedef unsigned short u16;
typedef unsigned int u32;
typedef __attribute__((ext_vector_type(8))) __bf16 bf16x8;
typedef __attribute__((ext_vector_type(4))) u16 ushort4v;
typedef __attribute__((ext_vector_type(4))) float f32x4;

// round-half-up bf16 pack: 2 VALU ops; differs from RNE only on exact ties
static __device__ __forceinline__ u16 f2bf(float f) {
    union { float f; u32 i; } c; c.f = f;
    return (u16)((c.i + 0x8000u) >> 16);
}
static __device__ __forceinline__ void async_copy16(const void* g, void* l) {
    __builtin_amdgcn_global_load_lds(
        (const __attribute__((address_space(1))) u32*)g,
        (__attribute__((address_space(3))) u32*)l, 16, 0, 0);
}

// ---------------- f32 -> bf16 convert (x) ----------------
__global__ __launch_bounds__(256) void convert_f32_bf16(const float* __restrict__ in,
                                                        u16* __restrict__ out) {
    const int i = (blockIdx.x * 256 + threadIdx.x) * 4;
    float4 v = *(const float4*)&in[i];
    ushort4v o;
    o[0] = f2bf(v.x); o[1] = f2bf(v.y); o[2] = f2bf(v.z); o[3] = f2bf(v.w);
    *(ushort4v*)&out[i] = o;
}

// ------- weight transpose + convert: Wt[z*1024 + n][k] = bf16(W_z[k][n]) -------
__global__ __launch_bounds__(256) void transpose_w3(const float* __restrict__ W0,
                                                    const float* __restrict__ W1,
                                                    const float* __restrict__ W2,
                                                    u16* __restrict__ Wt) {
    __shared__ u16 tile[64][65];
    const int z = blockIdx.z;
    const float* W = (z == 0) ? W0 : (z == 1) ? W1 : W2;
    const int n0 = blockIdx.x * 64, k0 = blockIdx.y * 64;
    const int t = threadIdx.x;
    #pragma unroll
    for (int p = 0; p < 16; ++p) {
        int idx = p * 256 + t;
        int r = idx >> 6, c = idx & 63;
        tile[r][c] = f2bf(W[(size_t)(k0 + r) * D_MODEL + (n0 + c)]);
    }
    __syncthreads();
    #pragma unroll
    for (int p = 0; p < 16; ++p) {
        int idx = p * 256 + t;
        int r = idx >> 6, c = idx & 63;
        Wt[((size_t)z * D_MODEL + n0 + r) * D_MODEL + (k0 + c)] = tile[c][r];
    }
}

// ------------- C[m,n] = A[m,:]·Bt[n,:] + bias[n] -------------
// m201-style 8-phase 256x256 template: BK=64, 8 waves (2x4 within WG-quadrant),
// per phase = one 128x128 WG C-quadrant x K=64 (16 MFMA/wave), one half-tile
// staged per phase (distance 4-6 phases), counted vmcnt(4) at phases 4/8 only,
// setprio around MFMA clusters, XOR chunk-swizzled LDS (0 bank conflicts).
// qkv=1: N=3072 fused; sel=n0>>10: 0->q [b,h,s,d]; 1->k; 2->v^T [b,h,d,s]
// qkv=0: out-projection; A gathered from [b,h,s,d]; writes f32 [M, D_MODEL]
__global__ __launch_bounds__(512, 2) void gemm_bt(const u16* __restrict__ A,
                                                  const u16* __restrict__ Bt,
                                                  const float* __restrict__ b0,
                                                  const float* __restrict__ b1,
                                                  const float* __restrict__ b2,
                                                  void* __restrict__ o0,
                                                  void* __restrict__ o1,
                                                  void* __restrict__ o2,
                                                  int qkv) {
    // per dbuf: A 256x64 (16384 u16) + B 256x64; 2 dbufs (even/odd K-tile) = 128 KB
    __shared__ __attribute__((aligned(16))) u16 smem[65536];
    const int t = threadIdx.x;
    const int m0 = blockIdx.y * 256, n0 = blockIdx.x * 256;
    const int lane = t & 63, w = t >> 6;
    const int lm = lane & 15, quad = lane >> 4;
    const int wm2 = w >> 2, wn4 = w & 3;        // 2 x 4 sub-grid within quadrant

    f32x4 acc[8][4];
    #pragma unroll
    for (int i = 0; i < 8; ++i)
        #pragma unroll
        for (int j = 0; j < 4; ++j) acc[i][j] = (f32x4){0.f, 0.f, 0.f, 0.f};

    // stage one half-tile (128 rows x 64 cols bf16 = 16 KB = 512 thr x 2 x 16B)
    auto stage_half = [&](int type /*0=A,1=B*/, int half, int kt, int d) {
        u16* dst = smem + d * 32768 + type * 16384 + half * 8192;
        #pragma unroll
        for (int i = 0; i < 2; ++i) {
            const int idx = i * 512 + t;
            const int rl = idx >> 3, c = idx & 7;
            const int cs = c ^ (rl & 7);        // XOR chunk swizzle (src side)
            const u16* src;
            const int row = half * 128 + rl;
            if (type == 0) {
                if (qkv) {
                    src = A + (size_t)(m0 + row) * D_MODEL + kt * 64 + cs * 8;
                } else {
                    const int m = m0 + row;
                    src = A + ((size_t)((m >> 9) * NH + kt) * SEQ + (m & 511)) * DK + cs * 8;
                }
            } else {
                src = Bt + (size_t)(n0 + row) * D_MODEL + kt * 64 + cs * 8;
            }
            async_copy16(src, &dst[idx * 8]);
        }
    };

    // prologue: ktile0 (4 halves -> dbuf0) + A0,B0 of ktile1 (-> dbuf1)
    stage_half(0, 0, 0, 0); stage_half(0, 1, 0, 0);
    stage_half(1, 0, 0, 0); stage_half(1, 1, 0, 0);
    stage_half(0, 0, 1, 1); stage_half(1, 0, 1, 1);
    asm volatile("s_waitcnt vmcnt(4)" ::: "memory");   // ktile0 resident
    __builtin_amdgcn_s_barrier();

    bf16x8 a[4][2];          // A frags for current (tk, mh): reused across nh phases
    bf16x8 bbuf[2][2][2];    // B frags [nh][nf][ks]: reused across mh phases

    for (int it = 0; it < 8; ++it) {
        const int k1g = 2 * it + 1, k2g = 2 * it + 2, k3g = 2 * it + 3;
        #pragma unroll
        for (int p = 0; p < 8; ++p) {
            const int tk = p >> 2, d = tk;      // ktile 2it+tk lives in dbuf tk
            const int qq = p & 3, mh = qq >> 1, nh = qq & 1;
            const u16* As = smem + d * 32768 + mh * 8192;
            const u16* Bs = smem + d * 32768 + 16384 + nh * 8192;
            // ---- ds-loads for this phase (A on nh==0; B on mh==0) ----
            if (nh == 0) {
                #pragma unroll
                for (int mf = 0; mf < 4; ++mf) {
                    const int rl = wm2 * 64 + mf * 16 + lm;
                    #pragma unroll
                    for (int ks = 0; ks < 2; ++ks)
                        a[mf][ks] = *(const bf16x8*)&As[rl * 64 + (((ks * 4 + quad)) ^ (rl & 7)) * 8];
                }
            }
            if (mh == 0) {
                #pragma unroll
                for (int nf = 0; nf < 2; ++nf) {
                    const int rl = wn4 * 32 + nf * 16 + lm;
                    #pragma unroll
                    for (int ks = 0; ks < 2; ++ks)
                        bbuf[nh][nf][ks] = *(const bf16x8*)&Bs[rl * 64 + (((ks * 4 + quad)) ^ (rl & 7)) * 8];
                }
            }
            // ---- stage one half-tile (WAR-safe schedule; see header comment) ----
            if (p == 0)      stage_half(0, 1, k1g, 1);
            else if (p == 1) stage_half(1, 1, k1g, 1);
            else if (p == 2) { if (it < 7) stage_half(0, 0, k2g, 0); }
            else if (p == 3) { if (it < 7) stage_half(1, 0, k2g, 0); }
            else if (p == 4) { if (it < 7) stage_half(0, 1, k2g, 0); }
            else if (p == 5) { if (it < 7) stage_half(1, 1, k2g, 0); }
            else if (p == 6) { if (it < 7) stage_half(0, 0, k3g, 1); }
            else             { if (it < 7) stage_half(1, 0, k3g, 1); }
            __builtin_amdgcn_s_barrier();
            __builtin_amdgcn_s_setprio(1);
            #pragma unroll
            for (int ks = 0; ks < 2; ++ks)
                #pragma unroll
                for (int mf = 0; mf < 4; ++mf)
                    #pragma unroll
                    for (int nf = 0; nf < 2; ++nf)
                        acc[mh * 4 + mf][nh * 2 + nf] = __builtin_amdgcn_mfma_f32_16x16x32_bf16(
                            a[mf][ks], bbuf[nh][nf][ks], acc[mh * 4 + mf][nh * 2 + nf], 0, 0, 0);
            __builtin_amdgcn_s_setprio(0);
            if (p == 3) {
                if (it < 7) { asm volatile("s_waitcnt vmcnt(4)" ::: "memory"); }
                else        { asm volatile("s_waitcnt vmcnt(0)" ::: "memory"); }
            }
            if (p == 7 && it < 7) { asm volatile("s_waitcnt vmcnt(4)" ::: "memory"); }
            __builtin_amdgcn_s_barrier();
        }
    }

    __syncthreads();   // all LDS reads done; smem free for epilogue reuse
    // output coords: row = mh*128 + wm2*64 + mf*16 + quad*4 + r (i = mh*4+mf)
    //                col = nh*128 + wn4*32 + nf*16 + lm          (j = nh*2+nf)
    if (qkv) {
        const int sel = n0 >> 10;   // uniform per block
        const int h0 = (n0 & 1023) >> 6;
        if (sel == 2) {
            // v^T [b,h,d,s] via LDS transpose; 2 col-half passes; 128B stores
            u16 (*Cs)[264] = (u16(*)[264])smem;
            const int bb_ = m0 >> 9, s0v = m0 & 511;
            #pragma unroll
            for (int ch = 0; ch < 2; ++ch) {
                #pragma unroll
                for (int nf = 0; nf < 2; ++nf) {
                    const int j = ch * 2 + nf;
                    const int nl = wn4 * 32 + nf * 16 + lm;
                    const float bvv = b2[(n0 & 1023) + ch * 128 + nl];
                    #pragma unroll
                    for (int i = 0; i < 8; ++i) {
                        const int ml = (i >> 2) * 128 + wm2 * 64 + (i & 3) * 16 + quad * 4;
                        ushort4v pk;
                        #pragma unroll
                        for (int r = 0; r < 4; ++r) pk[r] = f2bf(acc[i][j][r] + bvv);
                        *(ushort4v*)&Cs[nl][ml] = pk;
                    }
                }
                __syncthreads();
                const int rowl = t >> 2, chk = t & 3;
                const int h = h0 + ch * 2 + (rowl >> 6), dd = rowl & 63;
                u16* dp = (u16*)o2 + ((size_t)(bb_ * NH + h) * DK + dd) * SEQ + s0v + chk * 64;
                #pragma unroll
                for (int c = 0; c < 8; ++c)
                    *(uint4*)&dp[c * 8] = *(const uint4*)&Cs[rowl][chk * 64 + c * 8];
                __syncthreads();
            }
        } else {
            u16* dst = sel ? (u16*)o1 : (u16*)o0;
            const float* bb2 = sel ? b1 : b0;
            u16 (*Cs)[264] = (u16(*)[264])smem;
            #pragma unroll
            for (int rh = 0; rh < 2; ++rh) {    // row half = mh
                #pragma unroll
                for (int j = 0; j < 4; ++j) {
                    const int nl = (j >> 1) * 128 + wn4 * 32 + (j & 1) * 16 + lm;
                    const float bvv = bb2[(n0 & 1023) + nl];
                    #pragma unroll
                    for (int mf = 0; mf < 4; ++mf) {
                        const int rr = wm2 * 64 + mf * 16 + quad * 4;
                        #pragma unroll
                        for (int r = 0; r < 4; ++r)
                            Cs[rr + r][nl] = f2bf(acc[rh * 4 + mf][j][r] + bvv);
                    }
                }
                __syncthreads();
                const int rr2 = t >> 2, hd = t & 3;
                const int m = m0 + rh * 128 + rr2;
                const int b = m >> 9, s = m & 511;
                const int h = h0 + hd;
                u16* dp = &dst[((size_t)(b * NH + h) * SEQ + s) * DK];
                #pragma unroll
                for (int c = 0; c < 8; ++c)
                    *(uint4*)&dp[c * 8] = *(const uint4*)&Cs[rr2][hd * 64 + c * 8];
                __syncthreads();
            }
        }
    } else {
        float (*Cs)[260] = (float(*)[260])smem;   // 64 x 260 f32 per pass
        #pragma unroll
        for (int ph = 0; ph < 4; ++ph) {
            const int pmh = ph >> 1, pw = ph & 1;
            if (wm2 == pw) {
                #pragma unroll
                for (int j = 0; j < 4; ++j) {
                    const int nl = (j >> 1) * 128 + wn4 * 32 + (j & 1) * 16 + lm;
                    const float bvv = b0[n0 + nl];
                    #pragma unroll
                    for (int mf = 0; mf < 4; ++mf) {
                        const int rr = mf * 16 + quad * 4;
                        #pragma unroll
                        for (int r = 0; r < 4; ++r)
                            Cs[rr + r][nl] = acc[pmh * 4 + mf][j][r] + bvv;
                    }
                }
            }
            __syncthreads();
            const int rr2 = t >> 3, cc = t & 7;
            float* dp = &((float*)o0)[(size_t)(m0 + ph * 64 + rr2) * D_MODEL + n0 + cc * 32];
            #pragma unroll
            for (int c = 0; c < 8; ++c)
                *(uint4*)&dp[c * 4] = *(const uint4*)&Cs[rr2][cc * 32 + c * 4];
            __syncthreads();
        }
    }
}

// -------- flash attention: block = (b, h, 64-row q tile); output [b,h,s,d] --------
// XCD swizzle for reads: all 8 q-tiles of one (b,h) share F mod 8 -> same XCD L2.
// K/V double-buffered via global_load_lds, XOR-swizzled chunks, 1 barrier/jt.
__global__ __launch_bounds__(256) void attn_flash(const u16* __restrict__ qg,
                                                  const u16* __restrict__ kg,
                                                  const u16* __restrict__ vTg,
                                                  const float* __restrict__ rel,
                                                  u16* __restrict__ aout) {
    __shared__ __attribute__((aligned(16))) u16 qt[64 * 64];
    __shared__ __attribute__((aligned(16))) u16 kt[2][64 * 64];
    __shared__ __attribute__((aligned(16))) u16 vt[2][64 * 64];  // V^T: [d][j_local]
    __shared__ u16 Pl[4][16][72];   // wave-private P
    __shared__ float biasb[576];

    const int t = threadIdx.x;
    const int lane = t & 63, w = t >> 6;
    const int lm = lane & 15, quad = lane >> 4;
    const int F = blockIdx.x;
    const int xcd = F & 7, qti = (F >> 3) & 7, grp = F >> 6;
    const int p = grp * 8 + xcd;          // (b,h) id
    const int h = p & 15, b = p >> 4;
    const int q0 = qti * 64;
    const size_t bh = (size_t)(b * NH + h);
    const u16* qb = qg + bh * SEQ * DK;
    const u16* kb = kg + bh * SEQ * DK;
    const u16* vb = vTg + bh * DK * SEQ;

    // qt staging (XOR-swizzled, plain vector loads)
    #pragma unroll
    for (int i = 0; i < 2; ++i) {
        const int chunk = i * 256 + t, row = chunk >> 3, c = chunk & 7;
        const int cs = c ^ (row & 7);
        *(uint4*)&qt[chunk * 8] = *(const uint4*)&qb[(q0 + row) * DK + cs * 8];
    }
    for (int u = t; u < 575; u += 256) biasb[u] = rel[(q0 + u) * NH + h];

    // preload jt=0 K/V into buffer 0 via DMA
    #pragma unroll
    for (int i = 0; i < 2; ++i) {
        const int chunk = i * 256 + t, row = chunk >> 3, c = chunk & 7;
        const int cs = c ^ (row & 7);
        async_copy16(kb + row * DK + cs * 8, &kt[0][chunk * 8]);
        async_copy16(vb + row * SEQ + cs * 8, &vt[0][chunk * 8]);
    }

    float lsum[4] = {0.f, 0.f, 0.f, 0.f};
    f32x4 o[4];
    #pragma unroll
    for (int sd = 0; sd < 4; ++sd) o[sd] = (f32x4){0.f, 0.f, 0.f, 0.f};

    const float scale = 0.125f;  // 1/sqrt(64)

    for (int jt = 0; jt < 8; ++jt) {
        __syncthreads();   // drains DMA for 'cur'; prior readers of 'nxt' done
        const int cur = jt & 1, nxt = cur ^ 1;
        if (jt < 7) {      // DMA next tile; overlaps compute below
            const int j1 = (jt + 1) * 64;
            #pragma unroll
            for (int i = 0; i < 2; ++i) {
                const int chunk = i * 256 + t, row = chunk >> 3, c = chunk & 7;
                const int cs = c ^ (row & 7);
                async_copy16(kb + (j1 + row) * DK + cs * 8, &kt[nxt][chunk * 8]);
                async_copy16(vb + row * SEQ + j1 + cs * 8, &vt[nxt][chunk * 8]);
            }
        }
        const int j0 = jt * 64;

        // ---- QK^T + exp (no max subtraction; scores small by construction) ----
        const int ra = w * 16 + lm;
        bf16x8 aq0 = *(const bf16x8*)&qt[ra * 64 + ((quad) ^ (ra & 7)) * 8];
        bf16x8 aq1 = *(const bf16x8*)&qt[ra * 64 + ((4 + quad) ^ (ra & 7)) * 8];
        #pragma unroll
        for (int js = 0; js < 4; ++js) {
            const int rb = js * 16 + lm;
            bf16x8 bk0 = *(const bf16x8*)&kt[cur][rb * 64 + ((quad) ^ (rb & 7)) * 8];
            bf16x8 bk1 = *(const bf16x8*)&kt[cur][rb * 64 + ((4 + quad) ^ (rb & 7)) * 8];
            f32x4 c = (f32x4){0.f, 0.f, 0.f, 0.f};
            c = __builtin_amdgcn_mfma_f32_16x16x32_bf16(aq0, bk0, c, 0, 0, 0);
            c = __builtin_amdgcn_mfma_f32_16x16x32_bf16(aq1, bk1, c, 0, 0, 0);
            const int jg = j0 + js * 16 + lm;
            #pragma unroll
            for (int r = 0; r < 4; ++r) {
                const int rl = w * 16 + quad * 4 + r;
                float e = __expf(c[r] * scale + biasb[rl + 511 - jg]);
                lsum[r] += e;
                Pl[w][quad * 4 + r][js * 16 + lm] = f2bf(e);
            }
        }

        // ---- PV (wave-private P, no barrier) ----
        bf16x8 ap0 = *(const bf16x8*)&Pl[w][lm][quad * 8];
        bf16x8 ap1 = *(const bf16x8*)&Pl[w][lm][32 + quad * 8];
        #pragma unroll
        for (int sd = 0; sd < 4; ++sd) {
            const int rv = sd * 16 + lm;
            bf16x8 bv0 = *(const bf16x8*)&vt[cur][rv * 64 + ((quad) ^ (rv & 7)) * 8];
            bf16x8 bv1 = *(const bf16x8*)&vt[cur][rv * 64 + ((4 + quad) ^ (rv & 7)) * 8];
            o[sd] = __builtin_amdgcn_mfma_f32_16x16x32_bf16(ap0, bv0, o[sd], 0, 0, 0);
            o[sd] = __builtin_amdgcn_mfma_f32_16x16x32_bf16(ap1, bv1, o[sd], 0, 0, 0);
        }
    }

    // ---- epilogue: normalize, wave-private LDS transpose, contiguous 32B/lane stores ----
    #pragma unroll
    for (int r = 0; r < 4; ++r) {
        float s = lsum[r];
        s += __shfl_xor(s, 1, 64);
        s += __shfl_xor(s, 2, 64);
        s += __shfl_xor(s, 4, 64);
        s += __shfl_xor(s, 8, 64);
        const float rinv = 1.0f / s;
        #pragma unroll
        for (int sd = 0; sd < 4; ++sd)
            Pl[w][quad * 4 + r][sd * 16 + lm] = f2bf(o[sd][r] * rinv);
    }
    const int rowl = lane >> 2, ch = lane & 3;   // 16 rows x 4 chunks of 32B
    u16* dp = aout + bh * SEQ * DK + (size_t)(q0 + w * 16 + rowl) * DK + ch * 16;
    *(uint4*)&dp[0] = *(const uint4*)&Pl[w][rowl][ch * 16];
    *(uint4*)&dp[8] = *(const uint4*)&Pl[w][rowl][ch * 16 + 8];
}

extern "C" void kernel_launch(void* const* d_in, const int* in_sizes, int n_in,
                              void* d_out, int out_size, void* d_ws, size_t ws_size,
                              hipStream_t stream) {
    const float* x   = (const float*)d_in[0];
    const float* Wq  = (const float*)d_in[2];
    const float* bq  = (const float*)d_in[3];
    const float* Wk  = (const float*)d_in[4];
    const float* bk  = (const float*)d_in[5];
    const float* Wv  = (const float*)d_in[6];
    const float* bv  = (const float*)d_in[7];
    const float* Wo  = (const float*)d_in[8];
    const float* bo  = (const float*)d_in[9];
    const float* rel = (const float*)d_in[10];
    float* out = (float*)d_out;

    u16* ws = (u16*)d_ws;
    const size_t WSZ = (size_t)D_MODEL * D_MODEL;   // 1M u16 (2 MB)
    const size_t TSZ = (size_t)M_TOT * D_MODEL;     // 8M u16 (16 MB)
    u16* Wt3 = ws;            // 6 MB (qkv concat); reused for Wo^T
    u16* xbf = Wt3 + 3 * WSZ;
    u16* qws = xbf + TSZ;
    u16* kws = qws + TSZ;
    u16* vws = kws + TSZ;     // stored transposed [b,h,d,s]
    u16* aws = xbf;           // xbf dead after qkv GEMM; attn out [b,h,s,d]

    dim3 tb(256);
    convert_f32_bf16<<<dim3(M_TOT * D_MODEL / 1024), tb, 0, stream>>>(x, xbf);
    transpose_w3<<<dim3(16, 16, 3), tb, 0, stream>>>(Wq, Wk, Wv, Wt3);
    gemm_bt<<<dim3(12, 32), dim3(512), 0, stream>>>(xbf, Wt3, bq, bk, bv, qws, kws, vws, 1);
    attn_flash<<<dim3(2048), tb, 0, stream>>>(qws, kws, vws, rel, aws);
    transpose_w3<<<dim3(16, 16, 1), tb, 0, stream>>>(Wo, Wo, Wo, Wt3);
    gemm_bt<<<dim3(4, 32), dim3(512), 0, stream>>>(aws, Wt3, bo, nullptr, nullptr,
                                                   (void*)out, nullptr, nullptr, 0);
}

// Round 3
// 258.031 us; speedup vs baseline: 1.4987x; 1.4987x over previous
//
#include <hip/hip_runtime.h>
#include <hip/hip_bf16.h>
#include <stdint.h>

#define D_MODEL 1024
#define NH 16
#define SEQ 512
#define DK 64
#define BATCH 16
#define M_TOT (BATCH*SEQ)   // 8192

typedef unsigned short u16;
typedef unsigned int u32;
typedef __attribute__((ext_vector_type(8))) __bf16 bf16x8;
typedef __attribute__((ext_vector_type(4))) u16 ushort4v;
typedef __attribute__((ext_vector_type(4))) float f32x4;

// round-half-up bf16 pack: 2 VALU ops; differs from RNE only on exact ties
static __device__ __forceinline__ u16 f2bf(float f) {
    union { float f; u32 i; } c; c.f = f;
    return (u16)((c.i + 0x8000u) >> 16);
}
static __device__ __forceinline__ void async_copy16(const void* g, void* l) {
    __builtin_amdgcn_global_load_lds(
        (const __attribute__((address_space(1))) u32*)g,
        (__attribute__((address_space(3))) u32*)l, 16, 0, 0);
}

// ---------------- f32 -> bf16 convert (x) ----------------
__global__ __launch_bounds__(256) void convert_f32_bf16(const float* __restrict__ in,
                                                        u16* __restrict__ out) {
    const int i = (blockIdx.x * 256 + threadIdx.x) * 4;
    float4 v = *(const float4*)&in[i];
    ushort4v o;
    o[0] = f2bf(v.x); o[1] = f2bf(v.y); o[2] = f2bf(v.z); o[3] = f2bf(v.w);
    *(ushort4v*)&out[i] = o;
}

// ------- weight transpose + convert: Wt[z*1024 + n][k] = bf16(W_z[k][n]) -------
__global__ __launch_bounds__(256) void transpose_w3(const float* __restrict__ W0,
                                                    const float* __restrict__ W1,
                                                    const float* __restrict__ W2,
                                                    u16* __restrict__ Wt) {
    __shared__ u16 tile[64][65];
    const int z = blockIdx.z;
    const float* W = (z == 0) ? W0 : (z == 1) ? W1 : W2;
    const int n0 = blockIdx.x * 64, k0 = blockIdx.y * 64;
    const int t = threadIdx.x;
    #pragma unroll
    for (int p = 0; p < 16; ++p) {
        int idx = p * 256 + t;
        int r = idx >> 6, c = idx & 63;
        tile[r][c] = f2bf(W[(size_t)(k0 + r) * D_MODEL + (n0 + c)]);
    }
    __syncthreads();
    #pragma unroll
    for (int p = 0; p < 16; ++p) {
        int idx = p * 256 + t;
        int r = idx >> 6, c = idx & 63;
        Wt[((size_t)z * D_MODEL + n0 + r) * D_MODEL + (k0 + c)] = tile[c][r];
    }
}

// ------------- C[m,n] = A[m,:]·Bt[n,:] + bias[n]  (async BT GEMM, XOR-swizzled LDS) -------------
// A is always row-contiguous [M, D_MODEL] bf16 (attn out is written flat now).
// qkv=1: N=3072 fused; sel=n0>>10: 0 -> q [b,h,s,d]; 1 -> k [b,h,s,d]; 2 -> v^T [b,h,d,s]
// qkv=0: out-projection; writes f32 [M, D_MODEL]
__global__ __launch_bounds__(256) void gemm_bt(const u16* __restrict__ A,
                                               const u16* __restrict__ Bt,
                                               const float* __restrict__ b0,
                                               const float* __restrict__ b1,
                                               const float* __restrict__ b2,
                                               void* __restrict__ o0,
                                               void* __restrict__ o1,
                                               void* __restrict__ o2,
                                               int qkv) {
    __shared__ __attribute__((aligned(16))) u16 smem[16896];
    u16* Asm = smem;
    u16* Bsm = smem + 8192;
    const int t = threadIdx.x;
    const int m0 = blockIdx.y * 128, n0 = blockIdx.x * 128;
    const int lane = t & 63, w = t >> 6;
    const int lm = lane & 15, quad = lane >> 4;
    const int wm = w >> 1, wn = w & 1;

    f32x4 acc[4][4];
    #pragma unroll
    for (int i = 0; i < 4; ++i)
        #pragma unroll
        for (int j = 0; j < 4; ++j) acc[i][j] = (f32x4){0.f, 0.f, 0.f, 0.f};

    for (int kt = 0; kt < D_MODEL / 64; ++kt) {
        const int k0 = kt * 64;
        __syncthreads();
        #pragma unroll
        for (int i = 0; i < 4; ++i) {
            int chunk = i * 256 + t;
            int row = chunk >> 3, c = chunk & 7;
            int cs = c ^ (row & 7);   // XOR swizzle
            async_copy16(A + (size_t)(m0 + row) * D_MODEL + k0 + cs * 8, &Asm[chunk * 8]);
        }
        #pragma unroll
        for (int i = 0; i < 4; ++i) {
            int chunk = i * 256 + t;
            int row = chunk >> 3, c = chunk & 7;
            int cs = c ^ (row & 7);
            async_copy16(Bt + (size_t)(n0 + row) * D_MODEL + k0 + cs * 8, &Bsm[chunk * 8]);
        }
        __syncthreads();
        #pragma unroll
        for (int ks = 0; ks < 64; ks += 32) {
            const int cbase = ks >> 3;
            bf16x8 af[4], bfv[4];
            #pragma unroll
            for (int im = 0; im < 4; ++im) {
                const int row = wm * 64 + im * 16 + lm;
                const int c = (cbase + quad) ^ (row & 7);
                af[im] = *(const bf16x8*)&Asm[row * 64 + c * 8];
            }
            #pragma unroll
            for (int in = 0; in < 4; ++in) {
                const int row = wn * 64 + in * 16 + lm;
                const int c = (cbase + quad) ^ (row & 7);
                bfv[in] = *(const bf16x8*)&Bsm[row * 64 + c * 8];
            }
            #pragma unroll
            for (int im = 0; im < 4; ++im)
                #pragma unroll
                for (int in = 0; in < 4; ++in)
                    acc[im][in] = __builtin_amdgcn_mfma_f32_16x16x32_bf16(
                        af[im], bfv[in], acc[im][in], 0, 0, 0);
        }
    }

    __syncthreads();   // all MFMA LDS reads done; smem free for epilogue reuse
    if (qkv) {
        const int sel = n0 >> 10;   // uniform per block
        if (sel == 2) {
            #pragma unroll
            for (int in = 0; in < 4; ++in) {
                const int nn = (n0 & 1023) + wn * 64 + in * 16 + lm;
                const float bv = b2[nn];
                const int h = nn >> 6, d = nn & 63;
                #pragma unroll
                for (int im = 0; im < 4; ++im) {
                    const int mb = m0 + wm * 64 + im * 16 + quad * 4;
                    const int b = mb >> 9, s = mb & 511;
                    ushort4v pk;
                    #pragma unroll
                    for (int r = 0; r < 4; ++r) pk[r] = f2bf(acc[im][in][r] + bv);
                    *(ushort4v*)&((u16*)o2)[((size_t)(b * NH + h) * DK + d) * SEQ + s] = pk;
                }
            }
        } else {
            u16* dst = sel ? (u16*)o1 : (u16*)o0;
            const float* bb = sel ? b1 : b0;
            u16 (*Cs)[132] = (u16(*)[132])smem;
            #pragma unroll
            for (int in = 0; in < 4; ++in) {
                const int nl = wn * 64 + in * 16 + lm;
                const float bv = bb[(n0 & 1023) + nl];
                #pragma unroll
                for (int im = 0; im < 4; ++im)
                    #pragma unroll
                    for (int r = 0; r < 4; ++r)
                        Cs[wm * 64 + im * 16 + quad * 4 + r][nl] =
                            f2bf(acc[im][in][r] + bv);
            }
            __syncthreads();
            const int rr = t >> 1, hh = t & 1;
            const int m = m0 + rr;
            const int b = m >> 9, s = m & 511;
            const int h = ((n0 & 1023) >> 6) + hh;
            u16* dp = &dst[((size_t)(b * NH + h) * SEQ + s) * DK];
            #pragma unroll
            for (int c = 0; c < 8; ++c)
                *(uint4*)&dp[c * 8] = *(const uint4*)&Cs[rr][hh * 64 + c * 8];
        }
    } else {
        float (*Cs)[132] = (float(*)[132])smem;
        #pragma unroll
        for (int ph = 0; ph < 2; ++ph) {
            if (wm == ph) {
                #pragma unroll
                for (int in = 0; in < 4; ++in) {
                    const int nl = wn * 64 + in * 16 + lm;
                    const float bv = b0[n0 + nl];
                    #pragma unroll
                    for (int im = 0; im < 4; ++im)
                        #pragma unroll
                        for (int r = 0; r < 4; ++r)
                            Cs[im * 16 + quad * 4 + r][nl] = acc[im][in][r] + bv;
                }
            }
            __syncthreads();
            const int rr = t >> 2, qq = t & 3;
            float* dp = &((float*)o0)[(size_t)(m0 + ph * 64 + rr) * D_MODEL + n0 + qq * 32];
            #pragma unroll
            for (int c = 0; c < 8; ++c)
                *(uint4*)&dp[c * 4] = *(const uint4*)&Cs[rr][qq * 32 + c * 4];
            __syncthreads();
        }
    }
}

// -------- flash attention: block = (b, h, 64-row q tile); output FLAT [b,s,h*64+d] --------
// Swapped-operand MFMAs (T12 idea): QK^T computed as mfma(K,Q) -> S^T so each lane owns
// ONE q-row (lm) and 4 consecutive keys -> P written as 1 ds_write_b64 per js (was 16xb16);
// PV computed as mfma(V^T, P) -> O^T so rinv (per q=lm) applies lane-locally.
// K/V double-buffered via global_load_lds, XOR-swizzled chunks, 1 barrier/jt.
__global__ __launch_bounds__(256) void attn_flash(const u16* __restrict__ qg,
                                                  const u16* __restrict__ kg,
                                                  const u16* __restrict__ vTg,
                                                  const float* __restrict__ rel,
                                                  u16* __restrict__ aout) {
    __shared__ __attribute__((aligned(16))) u16 qt[64 * 64];
    __shared__ __attribute__((aligned(16))) u16 kt[2][64 * 64];
    __shared__ __attribute__((aligned(16))) u16 vt[2][64 * 64];  // V^T: [d][j_local]
    __shared__ __attribute__((aligned(16))) u16 Pl[4][16][72];   // wave-private P^ / O^ rows=q
    __shared__ float biasb[576];

    const int t = threadIdx.x;
    const int lane = t & 63, w = t >> 6;
    const int lm = lane & 15, quad = lane >> 4;
    const int F = blockIdx.x;
    const int xcd = F & 7, qti = (F >> 3) & 7, grp = F >> 6;
    const int p = grp * 8 + xcd;          // (b,h) id
    const int h = p & 15, b = p >> 4;
    const int q0 = qti * 64;
    const size_t bh = (size_t)(b * NH + h);
    const u16* qb = qg + bh * SEQ * DK;
    const u16* kb = kg + bh * SEQ * DK;
    const u16* vb = vTg + bh * DK * SEQ;

    // qt staging (XOR-swizzled, plain vector loads)
    #pragma unroll
    for (int i = 0; i < 2; ++i) {
        const int chunk = i * 256 + t, row = chunk >> 3, c = chunk & 7;
        const int cs = c ^ (row & 7);
        *(uint4*)&qt[chunk * 8] = *(const uint4*)&qb[(q0 + row) * DK + cs * 8];
    }
    for (int u = t; u < 575; u += 256) biasb[u] = rel[(q0 + u) * NH + h];

    // preload jt=0 K/V into buffer 0 via DMA
    #pragma unroll
    for (int i = 0; i < 2; ++i) {
        const int chunk = i * 256 + t, row = chunk >> 3, c = chunk & 7;
        const int cs = c ^ (row & 7);
        async_copy16(kb + row * DK + cs * 8, &kt[0][chunk * 8]);
        async_copy16(vb + row * SEQ + cs * 8, &vt[0][chunk * 8]);
    }

    float lsum = 0.f;
    f32x4 o[4];
    #pragma unroll
    for (int sd = 0; sd < 4; ++sd) o[sd] = (f32x4){0.f, 0.f, 0.f, 0.f};

    const float scale = 0.125f;  // 1/sqrt(64)

    for (int jt = 0; jt < 8; ++jt) {
        __syncthreads();   // drains DMA for 'cur'; prior readers of 'nxt' done
        const int cur = jt & 1, nxt = cur ^ 1;
        if (jt < 7) {      // DMA next tile; overlaps compute below
            const int j1 = (jt + 1) * 64;
            #pragma unroll
            for (int i = 0; i < 2; ++i) {
                const int chunk = i * 256 + t, row = chunk >> 3, c = chunk & 7;
                const int cs = c ^ (row & 7);
                async_copy16(kb + (j1 + row) * DK + cs * 8, &kt[nxt][chunk * 8]);
                async_copy16(vb + row * SEQ + j1 + cs * 8, &vt[nxt][chunk * 8]);
            }
        }
        const int j0 = jt * 64;

        // ---- S^T = K·Q^T + exp: lane owns q-row lm, keys js*16+quad*4+r ----
        const int ra = w * 16 + lm;
        bf16x8 aq0 = *(const bf16x8*)&qt[ra * 64 + ((quad) ^ (ra & 7)) * 8];
        bf16x8 aq1 = *(const bf16x8*)&qt[ra * 64 + ((4 + quad) ^ (ra & 7)) * 8];
        #pragma unroll
        for (int js = 0; js < 4; ++js) {
            const int rb = js * 16 + lm;
            bf16x8 bk0 = *(const bf16x8*)&kt[cur][rb * 64 + ((quad) ^ (rb & 7)) * 8];
            bf16x8 bk1 = *(const bf16x8*)&kt[cur][rb * 64 + ((4 + quad) ^ (rb & 7)) * 8];
            f32x4 c = (f32x4){0.f, 0.f, 0.f, 0.f};
            c = __builtin_amdgcn_mfma_f32_16x16x32_bf16(bk0, aq0, c, 0, 0, 0);
            c = __builtin_amdgcn_mfma_f32_16x16x32_bf16(bk1, aq1, c, 0, 0, 0);
            const int bb0 = w * 16 + lm + 511 - j0 - js * 16 - quad * 4;
            ushort4v pk;
            #pragma unroll
            for (int r = 0; r < 4; ++r) {
                float e = __expf(c[r] * scale + biasb[bb0 - r]);
                lsum += e;
                pk[r] = f2bf(e);
            }
            *(ushort4v*)&Pl[w][lm][js * 16 + quad * 4] = pk;   // one b64 write
        }

        // ---- O^T += V^T · P^T  (wave-private P, no barrier) ----
        bf16x8 ap0 = *(const bf16x8*)&Pl[w][lm][quad * 8];        // keys 0..31
        bf16x8 ap1 = *(const bf16x8*)&Pl[w][lm][32 + quad * 8];   // keys 32..63
        #pragma unroll
        for (int sd = 0; sd < 4; ++sd) {
            const int rv = sd * 16 + lm;
            bf16x8 bv0 = *(const bf16x8*)&vt[cur][rv * 64 + ((quad) ^ (rv & 7)) * 8];
            bf16x8 bv1 = *(const bf16x8*)&vt[cur][rv * 64 + ((4 + quad) ^ (rv & 7)) * 8];
            o[sd] = __builtin_amdgcn_mfma_f32_16x16x32_bf16(bv0, ap0, o[sd], 0, 0, 0);
            o[sd] = __builtin_amdgcn_mfma_f32_16x16x32_bf16(bv1, ap1, o[sd], 0, 0, 0);
        }
    }

    // ---- epilogue: q-row sum across quads, normalize lane-locally, transpose, store ----
    float s = lsum;
    s += __shfl_xor(s, 16, 64);
    s += __shfl_xor(s, 32, 64);
    const float rinv = 1.0f / s;
    #pragma unroll
    for (int sd = 0; sd < 4; ++sd) {
        ushort4v pk;
        #pragma unroll
        for (int r = 0; r < 4; ++r) pk[r] = f2bf(o[sd][r] * rinv);
        *(ushort4v*)&Pl[w][lm][sd * 16 + quad * 4] = pk;   // O rows = q_rel
    }
    const int rowl = lane >> 2, ch = lane & 3;   // 16 rows x 4 chunks of 32B
    u16* dp = aout + (size_t)(b * SEQ + q0 + w * 16 + rowl) * D_MODEL + h * DK + ch * 16;
    *(uint4*)&dp[0] = *(const uint4*)&Pl[w][rowl][ch * 16];
    *(uint4*)&dp[8] = *(const uint4*)&Pl[w][rowl][ch * 16 + 8];
}

extern "C" void kernel_launch(void* const* d_in, const int* in_sizes, int n_in,
                              void* d_out, int out_size, void* d_ws, size_t ws_size,
                              hipStream_t stream) {
    const float* x   = (const float*)d_in[0];
    const float* Wq  = (const float*)d_in[2];
    const float* bq  = (const float*)d_in[3];
    const float* Wk  = (const float*)d_in[4];
    const float* bk  = (const float*)d_in[5];
    const float* Wv  = (const float*)d_in[6];
    const float* bv  = (const float*)d_in[7];
    const float* Wo  = (const float*)d_in[8];
    const float* bo  = (const float*)d_in[9];
    const float* rel = (const float*)d_in[10];
    float* out = (float*)d_out;

    u16* ws = (u16*)d_ws;
    const size_t WSZ = (size_t)D_MODEL * D_MODEL;   // 1M u16 (2 MB)
    const size_t TSZ = (size_t)M_TOT * D_MODEL;     // 8M u16 (16 MB)
    u16* Wt3 = ws;            // 6 MB (qkv concat); reused for Wo^T
    u16* xbf = Wt3 + 3 * WSZ;
    u16* qws = xbf + TSZ;
    u16* kws = qws + TSZ;
    u16* vws = kws + TSZ;     // stored transposed [b,h,d,s]
    u16* aws = xbf;           // xbf dead after qkv GEMM; attn out FLAT [M, D_MODEL]

    dim3 tb(256);
    convert_f32_bf16<<<dim3(M_TOT * D_MODEL / 1024), tb, 0, stream>>>(x, xbf);
    transpose_w3<<<dim3(16, 16, 3), tb, 0, stream>>>(Wq, Wk, Wv, Wt3);
    gemm_bt<<<dim3(24, 64), tb, 0, stream>>>(xbf, Wt3, bq, bk, bv, qws, kws, vws, 1);
    attn_flash<<<dim3(2048), tb, 0, stream>>>(qws, kws, vws, rel, aws);
    transpose_w3<<<dim3(16, 16, 1), tb, 0, stream>>>(Wo, Wo, Wo, Wt3);
    gemm_bt<<<dim3(8, 64), tb, 0, stream>>>(aws, Wt3, bo, nullptr, nullptr,
                                            (void*)out, nullptr, nullptr, 0);
}